// Round 14
// baseline (218.562 us; speedup 1.0000x reference)
//
#include <hip/hip_runtime.h>
#include <hip/hip_bf16.h>

// ParallelGNNBlock: out = concat(0.99 * GCN_sparse(x,W1,b1), 0.01 * GCN_2hop(x,W2,b2))
// N=8192 nodes, D_IN=512, D_OUT=128, E=131072 edges.
//
// Pipeline (8 dispatches):
//  1. k_zero    : zero cnt/fill/AT bitset
//  2. k_hist    : in-degree histogram over dst
//  3. k_scan    : exclusive prefix sum -> row_ptr; dinv1 = rsqrt(deg+1)
//  4. k_scatter : CSR src lists by dst + AT bitset (AT[d] bit s <=> edge s->d)
//  5. k_a2t     : 2-hop union of AT rows -> EXPANDED adj2 lists + deg2 + dinv2
//  6. k_prep    : xh/xl split of x  +  BcatT weight transpose    (fused)
//  7. k_gemm    : MFMA bf16: g1 = dinv1.*(xh@W1h+xh@W1l+xl@W1h) f32 (K=1536)
//                            g2b = bf16(dinv2.*(xh@W2b))            (K=512)
//  8. k_spmm    : out[:, :128] (CSR gather) + out[:,128:] (adj2 list gather)

#define NN   8192
#define NE   131072
#define DIN  512
#define DO   128
#define A2S  512    // adj2 row stride (mean deg2~253, sigma~16 -> >16 sigma headroom)

using u64 = unsigned long long;
typedef __attribute__((ext_vector_type(8))) short short8v;
typedef __attribute__((ext_vector_type(4))) float f32x4;

// ---------------- workspace layout (bytes), ~39.6 MB ----------------
static constexpr size_t OFF_G1   = 0;                       // 4 MB f32
static constexpr size_t OFF_G2B  = OFF_G1   + 4194304;      // 2 MB bf16
static constexpr size_t OFF_AT   = OFF_G2B  + 2097152;      // 8 MB u64[8192][128]
static constexpr size_t OFF_ADJ2 = OFF_AT   + 8388608;      // 8 MB ushort[8192][512]
static constexpr size_t OFF_XH   = OFF_ADJ2 + 8388608;      // 8 MB bf16[8192][512]
static constexpr size_t OFF_XL   = OFF_XH   + 8388608;      // 8 MB
static constexpr size_t OFF_BT   = OFF_XL   + 8388608;      // 768 KB bf16[256][1536]
static constexpr size_t OFF_CNT  = OFF_BT   + 786432;       // 32 KB
static constexpr size_t OFF_FILL = OFF_CNT  + 32768;        // 32 KB
static constexpr size_t OFF_RP   = OFF_FILL + 32768;        // 33 KB
static constexpr size_t OFF_CSR  = OFF_RP   + 33024;        // 512 KB
static constexpr size_t OFF_DI1  = OFF_CSR  + 524288;       // 32 KB
static constexpr size_t OFF_DI2  = OFF_DI1  + 32768;        // 32 KB
static constexpr size_t OFF_DEG2 = OFF_DI2  + 32768;        // 32 KB

__device__ __forceinline__ unsigned short f2bf(float f) {
  unsigned u = __float_as_uint(f);
  return (unsigned short)((u + 0x7fffu + ((u >> 16) & 1u)) >> 16);   // RNE
}
__device__ __forceinline__ float bf2f(unsigned short h) {
  return __uint_as_float((unsigned)h << 16);
}
__device__ __forceinline__ void load_lds16(const void* g, void* l) {
  __builtin_amdgcn_global_load_lds((const __attribute__((address_space(1))) void*)g,
                                   (__attribute__((address_space(3))) void*)l, 16, 0, 0);
}

// ---------------- kernels ----------------

__global__ void k_zero(u64* __restrict__ AT,
                       unsigned* __restrict__ cnt, unsigned* __restrict__ fill) {
  size_t tid = (size_t)blockIdx.x * blockDim.x + threadIdx.x;
  size_t stride = (size_t)gridDim.x * blockDim.x;
  for (size_t i = tid; i < (size_t)NN * 128; i += stride) AT[i] = 0ull;
  if (tid < NN) { cnt[tid] = 0u; fill[tid] = 0u; }
}

__global__ void k_hist(const int* __restrict__ ei, unsigned* __restrict__ cnt) {
  int e = blockIdx.x * blockDim.x + threadIdx.x;
  if (e >= NE) return;
  atomicAdd(&cnt[ei[NE + e]], 1u);
}

__global__ __launch_bounds__(1024) void k_scan(const unsigned* __restrict__ cnt,
                                               unsigned* __restrict__ row_ptr,
                                               float* __restrict__ dinv1) {
  __shared__ unsigned sums[1024];
  int t = threadIdx.x;
  unsigned v[8];
  unsigned s = 0;
  #pragma unroll
  for (int i = 0; i < 8; i++) { v[i] = cnt[t * 8 + i]; s += v[i]; }
  sums[t] = s;
  __syncthreads();
  for (int off = 1; off < 1024; off *= 2) {
    unsigned add = (t >= off) ? sums[t - off] : 0u;
    __syncthreads();
    sums[t] += add;
    __syncthreads();
  }
  unsigned base = (t == 0) ? 0u : sums[t - 1];
  #pragma unroll
  for (int i = 0; i < 8; i++) {
    row_ptr[t * 8 + i] = base;
    base += v[i];
    dinv1[t * 8 + i] = rsqrtf((float)v[i] + 1.0f);
  }
  if (t == 1023) row_ptr[NN] = base;   // = NE
}

__global__ void k_scatter(const int* __restrict__ ei, const unsigned* __restrict__ row_ptr,
                          unsigned* __restrict__ fill, unsigned* __restrict__ csr_src,
                          u64* __restrict__ AT) {
  int e = blockIdx.x * blockDim.x + threadIdx.x;
  if (e >= NE) return;
  int s = ei[e];
  int d = ei[NE + e];
  unsigned pos = atomicAdd(&fill[d], 1u);
  csr_src[row_ptr[d] + pos] = (unsigned)s;
  atomicOr(&AT[(size_t)d * 128 + (s >> 6)], 1ull << (s & 63));
}

// 2-hop: union of AT[k] over k in bits(AT[i]) -> expanded list adj2[i][*],
// deg2[i] = popcount(union), dinv2[i] = rsqrt(deg2+1). No bitset output.
__global__ __launch_bounds__(512) void k_a2t(const u64* __restrict__ AT,
                                             unsigned short* __restrict__ adj2,
                                             unsigned* __restrict__ deg2,
                                             float* __restrict__ dinv2) {
  const int i = blockIdx.x, t = threadIdx.x;
  __shared__ unsigned pc[128];
  __shared__ unsigned short list[512];
  __shared__ u64 redB[4][128];
  __shared__ u64 uni[128];
  // ---- 1-hop source list from AT[i] ----
  u64 w0 = 0ull;
  if (t < 128) {
    w0 = AT[(size_t)i * 128 + t];
    pc[t] = (unsigned)__popcll(w0);
  }
  __syncthreads();
  for (int off = 1; off < 128; off <<= 1) {
    unsigned add = (t >= off && t < 128) ? pc[t - off] : 0u;
    __syncthreads();
    if (t < 128) pc[t] += add;
    __syncthreads();
  }
  if (t < 128) {
    unsigned base = (t == 0) ? 0u : pc[t - 1];
    u64 m = w0;
    while (m) {
      int b = __ffsll(m) - 1;
      m &= m - 1;
      list[base++] = (unsigned short)(t * 64 + b);
    }
  }
  __syncthreads();
  const unsigned total1 = pc[127];
  // ---- union of neighbor rows (4-way k-split) ----
  const int q = t >> 7, c = t & 127;
  u64 acc = 0ull;
  #pragma unroll 4
  for (unsigned k = q; k < total1; k += 4)
    acc |= AT[(size_t)list[k] * 128 + c];
  redB[q][c] = acc;
  __syncthreads();
  if (t < 128) {
    u64 u = redB[0][t] | redB[1][t] | redB[2][t] | redB[3][t];
    uni[t] = u;
    pc[t] = (unsigned)__popcll(u);
  }
  __syncthreads();
  // ---- scan popcounts, expand union bits -> adj2 list ----
  for (int off = 1; off < 128; off <<= 1) {
    unsigned add = (t >= off && t < 128) ? pc[t - off] : 0u;
    __syncthreads();
    if (t < 128) pc[t] += add;
    __syncthreads();
  }
  if (t < 128) {
    unsigned base = (t == 0) ? 0u : pc[t - 1];
    u64 m = uni[t];
    unsigned short* arow = &adj2[(size_t)i * A2S];
    while (m) {
      int b = __ffsll(m) - 1;
      m &= m - 1;
      if (base < A2S) arow[base] = (unsigned short)(t * 64 + b);
      base++;
    }
  }
  if (t == 0) {
    unsigned tot = pc[127];
    if (tot > A2S) tot = A2S;   // statistically unreachable guard
    deg2[i] = tot;
    dinv2[i] = rsqrtf((float)pc[127] + 1.0f);
  }
}

// Fused: blocks <2048 do xh/xl split; blocks 2048..2079 do weight transpose.
// BcatT[n][k]: n<128 -> [W1h(0:512) | W1l(512:1024) | W1h(1024:1536)];
//             n>=128 -> W2 bf16 in k<512 (rest never read).
__global__ __launch_bounds__(256) void k_prep(const float* __restrict__ x,
                                              const float* __restrict__ W1,
                                              const float* __restrict__ W2,
                                              unsigned short* __restrict__ xh,
                                              unsigned short* __restrict__ xl,
                                              unsigned short* __restrict__ Bt) {
  if (blockIdx.x < 2048) {
    size_t i = (size_t)blockIdx.x * 256 + threadIdx.x;
    size_t stride = (size_t)2048 * 256;
    for (size_t p = i; p < (size_t)NN * DIN / 4; p += stride) {
      float4 v = ((const float4*)x)[p];
      ushort4 h, l;
      h.x = f2bf(v.x); l.x = f2bf(v.x - bf2f(h.x));
      h.y = f2bf(v.y); l.y = f2bf(v.y - bf2f(h.y));
      h.z = f2bf(v.z); l.z = f2bf(v.z - bf2f(h.z));
      h.w = f2bf(v.w); l.w = f2bf(v.w - bf2f(h.w));
      ((ushort4*)xh)[p] = h;
      ((ushort4*)xl)[p] = l;
    }
  } else {
    const int t = (blockIdx.x - 2048) * 256 + threadIdx.x;   // 0..8191
    const int n = t & 127, kb = (t >> 7) << 3;               // 8 consecutive k
    short8v vh, vl, v2;
    #pragma unroll
    for (int j = 0; j < 8; j++) {
      float w = W1[(size_t)(kb + j) * DO + n];
      unsigned short h = f2bf(w);
      vh[j] = (short)h;
      vl[j] = (short)f2bf(w - bf2f(h));
      v2[j] = (short)f2bf(W2[(size_t)(kb + j) * DO + n]);
    }
    unsigned short* r1 = &Bt[(size_t)n * 1536];
    *(short8v*)&r1[kb]        = vh;
    *(short8v*)&r1[512 + kb]  = vl;
    *(short8v*)&r1[1024 + kb] = vh;
    *(short8v*)&Bt[(size_t)(128 + n) * 1536 + kb] = v2;
  }
}

// MFMA GEMM: 64x64 tile, 4 waves (2x2), each wave 32x32 (2x2 16x16x32 frags).
// bn<2: K=1536 (W1 hi/lo triple) -> g1 f32.  bn>=2: K=512 (W2) -> g2b bf16.
// LDS in FRAGMENT ORDER (linear dest, per-lane global src encodes mapping):
// combo=rowgrp*2+khalf; lane l's 16B at combo*1024+l*16. ds_read_b128 is
// stride-16B across lanes: conflict-free.
__global__ __launch_bounds__(256) void k_gemm(const unsigned short* __restrict__ xh,
                                              const unsigned short* __restrict__ xl,
                                              const unsigned short* __restrict__ Bt,
                                              const float* __restrict__ dinv1,
                                              const float* __restrict__ dinv2,
                                              float* __restrict__ g1,
                                              unsigned short* __restrict__ g2b) {
  const int bm = blockIdx.x, bn = blockIdx.y;
  const int Kext = (bn < 2) ? 1536 : 512;
  __shared__ __align__(16) unsigned short As[4096];   // 8 KB
  __shared__ __align__(16) unsigned short Bs[4096];   // 8 KB
  const int tid = threadIdx.x;
  const int lane = tid & 63, wv = tid >> 6;
  const int wr = wv >> 1, wc = wv & 1;

  const int c0 = tid, c1 = tid + 256;
  const int cb0 = c0 >> 6, l0 = c0 & 63;
  const int cb1 = c1 >> 6, l1 = c1 & 63;
  const int rT0 = (cb0 >> 1) * 16 + (l0 & 15), kc0 = (cb0 & 1) * 4 + (l0 >> 4);
  const int rT1 = (cb1 >> 1) * 16 + (l1 & 15), kc1 = (cb1 & 1) * 4 + (l1 >> 4);
  const size_t gA0 = (size_t)(bm * 64 + rT0) * DIN + kc0 * 8;
  const size_t gA1 = (size_t)(bm * 64 + rT1) * DIN + kc1 * 8;
  const size_t gB0 = (size_t)(bn * 64 + rT0) * 1536 + kc0 * 8;
  const size_t gB1 = (size_t)(bn * 64 + rT1) * 1536 + kc1 * 8;

  const int lofs = lane * 8;                        // shorts

  f32x4 acc00 = {0.f, 0.f, 0.f, 0.f};
  f32x4 acc01 = acc00, acc10 = acc00, acc11 = acc00;

  for (int k0 = 0; k0 < Kext; k0 += 64) {
    const unsigned short* sA =
        (k0 < 512) ? (xh + k0) : (k0 < 1024) ? (xh + (k0 - 512)) : (xl + (k0 - 1024));
    load_lds16(sA + gA0, &As[c0 * 8]);
    load_lds16(sA + gA1, &As[c1 * 8]);
    load_lds16(Bt + k0 + gB0, &Bs[c0 * 8]);
    load_lds16(Bt + k0 + gB1, &Bs[c1 * 8]);
    __syncthreads();
    #pragma unroll
    for (int ks = 0; ks < 2; ks++) {
      short8v a0 = *(const short8v*)&As[(wr * 4 + ks) * 512 + lofs];
      short8v a1 = *(const short8v*)&As[(wr * 4 + 2 + ks) * 512 + lofs];
      short8v b0 = *(const short8v*)&Bs[(wc * 4 + ks) * 512 + lofs];
      short8v b1 = *(const short8v*)&Bs[(wc * 4 + 2 + ks) * 512 + lofs];
      acc00 = __builtin_amdgcn_mfma_f32_16x16x32_bf16(a0, b0, acc00, 0, 0, 0);
      acc01 = __builtin_amdgcn_mfma_f32_16x16x32_bf16(a0, b1, acc01, 0, 0, 0);
      acc10 = __builtin_amdgcn_mfma_f32_16x16x32_bf16(a1, b0, acc10, 0, 0, 0);
      acc11 = __builtin_amdgcn_mfma_f32_16x16x32_bf16(a1, b1, acc11, 0, 0, 0);
    }
    __syncthreads();
  }

  // epilogue: C/D layout col=lane&15, row=(lane>>4)*4+r  [m89-verified]
  const int colb = lane & 15;
  const int rowb = (lane >> 4) << 2;
  #pragma unroll
  for (int m = 0; m < 2; m++) {
    #pragma unroll
    for (int n = 0; n < 2; n++) {
      f32x4 a = (m == 0) ? (n == 0 ? acc00 : acc01) : (n == 0 ? acc10 : acc11);
      const int cl = wc * 32 + n * 16 + colb;
      #pragma unroll
      for (int r = 0; r < 4; r++) {
        const int gr = bm * 64 + wr * 32 + m * 16 + rowb + r;
        if (bn < 2) {
          const int gc = bn * 64 + cl;
          g1[(size_t)gr * DO + gc] = dinv1[gr] * a[r];
        } else {
          const int gc = (bn - 2) * 64 + cl;
          g2b[(size_t)gr * DO + gc] = f2bf(dinv2[gr] * a[r]);
        }
      }
    }
  }
}

// Fused spmm: 256 threads per node. LDS only redA (4 KB) -> 8 blocks/CU.
// Phase 1 (cols 0:128): CSR gather over g1 (f32), 4-way edge split, float2/lane.
// Phase 2 (cols 128:256): adj2-list gather over g2b (bf16), 8-way k-split,
//                         uint2 (4 bf16) per lane, 32 lanes per row.
__global__ __launch_bounds__(256) void k_spmm(const float* __restrict__ g1,
                                              const unsigned* __restrict__ row_ptr,
                                              const unsigned* __restrict__ csr_src,
                                              const float* __restrict__ dinv1,
                                              const float* __restrict__ b1,
                                              const unsigned short* __restrict__ g2b,
                                              const unsigned short* __restrict__ adj2,
                                              const unsigned* __restrict__ deg2,
                                              const float* __restrict__ dinv2,
                                              const float* __restrict__ b2,
                                              float* __restrict__ out) {
  const int i = blockIdx.x, t = threadIdx.x;
  __shared__ float redA[8][128];

  // ---- phase 1: 1-hop CSR ----
  {
    const int q = t >> 6, c = t & 63;
    const unsigned lo = row_ptr[i], hi = row_ptr[i + 1];
    float a0 = 0.f, a1 = 0.f;
    #pragma unroll 4
    for (unsigned e = lo + q; e < hi; e += 4) {
      unsigned j = csr_src[e];
      float2 v = *(const float2*)&g1[(size_t)j * DO + 2 * c];
      a0 += v.x; a1 += v.y;
    }
    redA[q][2 * c] = a0;
    redA[q][2 * c + 1] = a1;
    __syncthreads();
    if (t < 128) {
      float s = g1[(size_t)i * DO + t]          // self-loop term (dinv^2*h)
              + redA[0][t] + redA[1][t] + redA[2][t] + redA[3][t];
      out[(size_t)i * 256 + t] = 0.99f * (dinv1[i] * s + b1[t]);
    }
  }
  __syncthreads();

  // ---- phase 2: 2-hop via precomputed adj2 list ----
  const unsigned total = deg2[i];
  const unsigned short* arow = &adj2[(size_t)i * A2S];
  const int q = t >> 5, c = t & 31;            // 8-way; uint2 = 4 bf16 per lane
  float a0 = 0.f, a1 = 0.f, a2 = 0.f, a3 = 0.f;
  #pragma unroll 4
  for (unsigned k = q; k < total; k += 8) {
    unsigned j = arow[k];                       // 32-lane broadcast read
    uint2 u = *(const uint2*)&g2b[(size_t)j * DO + 4 * c];
    a0 += __uint_as_float(u.x << 16);
    a1 += __uint_as_float(u.x & 0xffff0000u);
    a2 += __uint_as_float(u.y << 16);
    a3 += __uint_as_float(u.y & 0xffff0000u);
  }
  redA[q][4 * c]     = a0;
  redA[q][4 * c + 1] = a1;
  redA[q][4 * c + 2] = a2;
  redA[q][4 * c + 3] = a3;
  __syncthreads();
  if (t < 128) {
    float s = bf2f(g2b[(size_t)i * DO + t]);   // appended self-loop
    #pragma unroll
    for (int r = 0; r < 8; r++) s += redA[r][t];
    out[(size_t)i * 256 + 128 + t] = 0.01f * (dinv2[i] * s + b2[t]);
  }
}

// ---------------- launch ----------------

extern "C" void kernel_launch(void* const* d_in, const int* in_sizes, int n_in,
                              void* d_out, int out_size, void* d_ws, size_t ws_size,
                              hipStream_t stream) {
  const float* x  = (const float*)d_in[0];
  const int*   ei = (const int*)d_in[1];
  const float* W1 = (const float*)d_in[2];
  const float* b1 = (const float*)d_in[3];
  const float* W2 = (const float*)d_in[4];
  const float* b2 = (const float*)d_in[5];
  float* out = (float*)d_out;
  char* ws = (char*)d_ws;

  float* g1              = (float*)(ws + OFF_G1);
  unsigned short* g2b    = (unsigned short*)(ws + OFF_G2B);
  u64* AT                = (u64*)(ws + OFF_AT);
  unsigned short* adj2   = (unsigned short*)(ws + OFF_ADJ2);
  unsigned short* xh     = (unsigned short*)(ws + OFF_XH);
  unsigned short* xl     = (unsigned short*)(ws + OFF_XL);
  unsigned short* Bt     = (unsigned short*)(ws + OFF_BT);
  unsigned* cnt          = (unsigned*)(ws + OFF_CNT);
  unsigned* fill         = (unsigned*)(ws + OFF_FILL);
  unsigned* row_ptr      = (unsigned*)(ws + OFF_RP);
  unsigned* csr_src      = (unsigned*)(ws + OFF_CSR);
  float* dinv1           = (float*)(ws + OFF_DI1);
  float* dinv2           = (float*)(ws + OFF_DI2);
  unsigned* deg2         = (unsigned*)(ws + OFF_DEG2);

  k_zero<<<1024, 256, 0, stream>>>(AT, cnt, fill);
  k_hist<<<NE / 256, 256, 0, stream>>>(ei, cnt);
  k_scan<<<1, 1024, 0, stream>>>(cnt, row_ptr, dinv1);
  k_scatter<<<NE / 256, 256, 0, stream>>>(ei, row_ptr, fill, csr_src, AT);
  k_a2t<<<NN, 512, 0, stream>>>(AT, adj2, deg2, dinv2);
  k_prep<<<2080, 256, 0, stream>>>(x, W1, W2, xh, xl, Bt);
  dim3 gg(NN / 64, 4);
  k_gemm<<<gg, 256, 0, stream>>>(xh, xl, Bt, dinv1, dinv2, g1, g2b);
  k_spmm<<<NN, 256, 0, stream>>>(g1, row_ptr, csr_src, dinv1, b1,
                                 g2b, adj2, deg2, dinv2, b2, out);
}

// Round 15
// 206.094 us; speedup vs baseline: 1.0605x; 1.0605x over previous
//
#include <hip/hip_runtime.h>
#include <hip/hip_bf16.h>

// ParallelGNNBlock: out = concat(0.99 * GCN_sparse(x,W1,b1), 0.01 * GCN_2hop(x,W2,b2))
// N=8192 nodes, D_IN=512, D_OUT=128, E=131072 edges.
//
// Pipeline (8 dispatches):
//  1. k_zero    : zero cnt/fill/AT bitset
//  2. k_hist    : in-degree histogram over dst
//  3. k_scan    : exclusive prefix sum -> row_ptr; dinv1 = rsqrt(deg+1)
//  4. k_scatter : CSR src lists by dst + AT bitset (AT[d] bit s <=> edge s->d)
//  5. k_a2t     : 2-hop union of AT rows -> EXPANDED adj2 lists + deg2 + dinv2
//  6. k_prep    : xh/xl split of x  +  BcatT weight transpose    (fused)
//  7. k_gemm    : MFMA bf16: g1 = dinv1.*(xh@W1h+xh@W1l+xl@W1h) f32 (K=1536)
//                            g2b = bf16(dinv2.*(xh@W2b))            (K=512)
//  8. k_spmm    : out[:, :128] (CSR gather) + out[:,128:] (adj2 gather,
//                 index row async-staged to LDS under phase 1)

#define NN   8192
#define NE   131072
#define DIN  512
#define DO   128
#define A2S  512    // adj2 row stride (mean deg2~253, sigma~16 -> >16 sigma headroom)

using u64 = unsigned long long;
typedef __attribute__((ext_vector_type(8))) short short8v;
typedef __attribute__((ext_vector_type(4))) float f32x4;

// ---------------- workspace layout (bytes), ~39.6 MB ----------------
static constexpr size_t OFF_G1   = 0;                       // 4 MB f32
static constexpr size_t OFF_G2B  = OFF_G1   + 4194304;      // 2 MB bf16
static constexpr size_t OFF_AT   = OFF_G2B  + 2097152;      // 8 MB u64[8192][128]
static constexpr size_t OFF_ADJ2 = OFF_AT   + 8388608;      // 8 MB ushort[8192][512]
static constexpr size_t OFF_XH   = OFF_ADJ2 + 8388608;      // 8 MB bf16[8192][512]
static constexpr size_t OFF_XL   = OFF_XH   + 8388608;      // 8 MB
static constexpr size_t OFF_BT   = OFF_XL   + 8388608;      // 768 KB bf16[256][1536]
static constexpr size_t OFF_CNT  = OFF_BT   + 786432;       // 32 KB
static constexpr size_t OFF_FILL = OFF_CNT  + 32768;        // 32 KB
static constexpr size_t OFF_RP   = OFF_FILL + 32768;        // 33 KB
static constexpr size_t OFF_CSR  = OFF_RP   + 33024;        // 512 KB
static constexpr size_t OFF_DI1  = OFF_CSR  + 524288;       // 32 KB
static constexpr size_t OFF_DI2  = OFF_DI1  + 32768;        // 32 KB
static constexpr size_t OFF_DEG2 = OFF_DI2  + 32768;        // 32 KB

__device__ __forceinline__ unsigned short f2bf(float f) {
  unsigned u = __float_as_uint(f);
  return (unsigned short)((u + 0x7fffu + ((u >> 16) & 1u)) >> 16);   // RNE
}
__device__ __forceinline__ float bf2f(unsigned short h) {
  return __uint_as_float((unsigned)h << 16);
}
__device__ __forceinline__ void load_lds16(const void* g, void* l) {
  __builtin_amdgcn_global_load_lds((const __attribute__((address_space(1))) void*)g,
                                   (__attribute__((address_space(3))) void*)l, 16, 0, 0);
}
__device__ __forceinline__ void load_lds4(const void* g, void* l) {
  __builtin_amdgcn_global_load_lds((const __attribute__((address_space(1))) void*)g,
                                   (__attribute__((address_space(3))) void*)l, 4, 0, 0);
}

// ---------------- kernels ----------------

__global__ void k_zero(u64* __restrict__ AT,
                       unsigned* __restrict__ cnt, unsigned* __restrict__ fill) {
  size_t tid = (size_t)blockIdx.x * blockDim.x + threadIdx.x;
  size_t stride = (size_t)gridDim.x * blockDim.x;
  for (size_t i = tid; i < (size_t)NN * 128; i += stride) AT[i] = 0ull;
  if (tid < NN) { cnt[tid] = 0u; fill[tid] = 0u; }
}

__global__ void k_hist(const int* __restrict__ ei, unsigned* __restrict__ cnt) {
  int e = blockIdx.x * blockDim.x + threadIdx.x;
  if (e >= NE) return;
  atomicAdd(&cnt[ei[NE + e]], 1u);
}

__global__ __launch_bounds__(1024) void k_scan(const unsigned* __restrict__ cnt,
                                               unsigned* __restrict__ row_ptr,
                                               float* __restrict__ dinv1) {
  __shared__ unsigned sums[1024];
  int t = threadIdx.x;
  unsigned v[8];
  unsigned s = 0;
  #pragma unroll
  for (int i = 0; i < 8; i++) { v[i] = cnt[t * 8 + i]; s += v[i]; }
  sums[t] = s;
  __syncthreads();
  for (int off = 1; off < 1024; off *= 2) {
    unsigned add = (t >= off) ? sums[t - off] : 0u;
    __syncthreads();
    sums[t] += add;
    __syncthreads();
  }
  unsigned base = (t == 0) ? 0u : sums[t - 1];
  #pragma unroll
  for (int i = 0; i < 8; i++) {
    row_ptr[t * 8 + i] = base;
    base += v[i];
    dinv1[t * 8 + i] = rsqrtf((float)v[i] + 1.0f);
  }
  if (t == 1023) row_ptr[NN] = base;   // = NE
}

__global__ void k_scatter(const int* __restrict__ ei, const unsigned* __restrict__ row_ptr,
                          unsigned* __restrict__ fill, unsigned* __restrict__ csr_src,
                          u64* __restrict__ AT) {
  int e = blockIdx.x * blockDim.x + threadIdx.x;
  if (e >= NE) return;
  int s = ei[e];
  int d = ei[NE + e];
  unsigned pos = atomicAdd(&fill[d], 1u);
  csr_src[row_ptr[d] + pos] = (unsigned)s;
  atomicOr(&AT[(size_t)d * 128 + (s >> 6)], 1ull << (s & 63));
}

// 2-hop: union of AT[k] over k in bits(AT[i]) -> expanded list adj2[i][*],
// deg2[i] = popcount(union), dinv2[i] = rsqrt(deg2+1). No bitset output.
__global__ __launch_bounds__(512) void k_a2t(const u64* __restrict__ AT,
                                             unsigned short* __restrict__ adj2,
                                             unsigned* __restrict__ deg2,
                                             float* __restrict__ dinv2) {
  const int i = blockIdx.x, t = threadIdx.x;
  __shared__ unsigned pc[128];
  __shared__ unsigned short list[512];
  __shared__ u64 redB[4][128];
  __shared__ u64 uni[128];
  // ---- 1-hop source list from AT[i] ----
  u64 w0 = 0ull;
  if (t < 128) {
    w0 = AT[(size_t)i * 128 + t];
    pc[t] = (unsigned)__popcll(w0);
  }
  __syncthreads();
  for (int off = 1; off < 128; off <<= 1) {
    unsigned add = (t >= off && t < 128) ? pc[t - off] : 0u;
    __syncthreads();
    if (t < 128) pc[t] += add;
    __syncthreads();
  }
  if (t < 128) {
    unsigned base = (t == 0) ? 0u : pc[t - 1];
    u64 m = w0;
    while (m) {
      int b = __ffsll(m) - 1;
      m &= m - 1;
      list[base++] = (unsigned short)(t * 64 + b);
    }
  }
  __syncthreads();
  const unsigned total1 = pc[127];
  // ---- union of neighbor rows (4-way k-split) ----
  const int q = t >> 7, c = t & 127;
  u64 acc = 0ull;
  #pragma unroll 4
  for (unsigned k = q; k < total1; k += 4)
    acc |= AT[(size_t)list[k] * 128 + c];
  redB[q][c] = acc;
  __syncthreads();
  if (t < 128) {
    u64 u = redB[0][t] | redB[1][t] | redB[2][t] | redB[3][t];
    uni[t] = u;
    pc[t] = (unsigned)__popcll(u);
  }
  __syncthreads();
  // ---- scan popcounts, expand union bits -> adj2 list ----
  for (int off = 1; off < 128; off <<= 1) {
    unsigned add = (t >= off && t < 128) ? pc[t - off] : 0u;
    __syncthreads();
    if (t < 128) pc[t] += add;
    __syncthreads();
  }
  if (t < 128) {
    unsigned base = (t == 0) ? 0u : pc[t - 1];
    u64 m = uni[t];
    unsigned short* arow = &adj2[(size_t)i * A2S];
    while (m) {
      int b = __ffsll(m) - 1;
      m &= m - 1;
      if (base < A2S) arow[base] = (unsigned short)(t * 64 + b);
      base++;
    }
  }
  if (t == 0) {
    unsigned tot = pc[127];
    if (tot > A2S) tot = A2S;   // statistically unreachable guard
    deg2[i] = tot;
    dinv2[i] = rsqrtf((float)pc[127] + 1.0f);
  }
}

// Fused: blocks <2048 do xh/xl split; blocks 2048..2079 do weight transpose.
// BcatT[n][k]: n<128 -> [W1h(0:512) | W1l(512:1024) | W1h(1024:1536)];
//             n>=128 -> W2 bf16 in k<512 (rest never read).
__global__ __launch_bounds__(256) void k_prep(const float* __restrict__ x,
                                              const float* __restrict__ W1,
                                              const float* __restrict__ W2,
                                              unsigned short* __restrict__ xh,
                                              unsigned short* __restrict__ xl,
                                              unsigned short* __restrict__ Bt) {
  if (blockIdx.x < 2048) {
    size_t i = (size_t)blockIdx.x * 256 + threadIdx.x;
    size_t stride = (size_t)2048 * 256;
    for (size_t p = i; p < (size_t)NN * DIN / 4; p += stride) {
      float4 v = ((const float4*)x)[p];
      ushort4 h, l;
      h.x = f2bf(v.x); l.x = f2bf(v.x - bf2f(h.x));
      h.y = f2bf(v.y); l.y = f2bf(v.y - bf2f(h.y));
      h.z = f2bf(v.z); l.z = f2bf(v.z - bf2f(h.z));
      h.w = f2bf(v.w); l.w = f2bf(v.w - bf2f(h.w));
      ((ushort4*)xh)[p] = h;
      ((ushort4*)xl)[p] = l;
    }
  } else {
    const int t = (blockIdx.x - 2048) * 256 + threadIdx.x;   // 0..8191
    const int n = t & 127, kb = (t >> 7) << 3;               // 8 consecutive k
    short8v vh, vl, v2;
    #pragma unroll
    for (int j = 0; j < 8; j++) {
      float w = W1[(size_t)(kb + j) * DO + n];
      unsigned short h = f2bf(w);
      vh[j] = (short)h;
      vl[j] = (short)f2bf(w - bf2f(h));
      v2[j] = (short)f2bf(W2[(size_t)(kb + j) * DO + n]);
    }
    unsigned short* r1 = &Bt[(size_t)n * 1536];
    *(short8v*)&r1[kb]        = vh;
    *(short8v*)&r1[512 + kb]  = vl;
    *(short8v*)&r1[1024 + kb] = vh;
    *(short8v*)&Bt[(size_t)(128 + n) * 1536 + kb] = v2;
  }
}

// MFMA GEMM: 64x64 tile, 4 waves (2x2), each wave 32x32 (2x2 16x16x32 frags).
// bn<2: K=1536 (W1 hi/lo triple) -> g1 f32.  bn>=2: K=512 (W2) -> g2b bf16.
// LDS in FRAGMENT ORDER (linear dest, per-lane global src encodes mapping):
// combo=rowgrp*2+khalf; lane l's 16B at combo*1024+l*16. ds_read_b128 is
// stride-16B across lanes: conflict-free.
__global__ __launch_bounds__(256) void k_gemm(const unsigned short* __restrict__ xh,
                                              const unsigned short* __restrict__ xl,
                                              const unsigned short* __restrict__ Bt,
                                              const float* __restrict__ dinv1,
                                              const float* __restrict__ dinv2,
                                              float* __restrict__ g1,
                                              unsigned short* __restrict__ g2b) {
  const int bm = blockIdx.x, bn = blockIdx.y;
  const int Kext = (bn < 2) ? 1536 : 512;
  __shared__ __align__(16) unsigned short As[4096];   // 8 KB
  __shared__ __align__(16) unsigned short Bs[4096];   // 8 KB
  const int tid = threadIdx.x;
  const int lane = tid & 63, wv = tid >> 6;
  const int wr = wv >> 1, wc = wv & 1;

  const int c0 = tid, c1 = tid + 256;
  const int cb0 = c0 >> 6, l0 = c0 & 63;
  const int cb1 = c1 >> 6, l1 = c1 & 63;
  const int rT0 = (cb0 >> 1) * 16 + (l0 & 15), kc0 = (cb0 & 1) * 4 + (l0 >> 4);
  const int rT1 = (cb1 >> 1) * 16 + (l1 & 15), kc1 = (cb1 & 1) * 4 + (l1 >> 4);
  const size_t gA0 = (size_t)(bm * 64 + rT0) * DIN + kc0 * 8;
  const size_t gA1 = (size_t)(bm * 64 + rT1) * DIN + kc1 * 8;
  const size_t gB0 = (size_t)(bn * 64 + rT0) * 1536 + kc0 * 8;
  const size_t gB1 = (size_t)(bn * 64 + rT1) * 1536 + kc1 * 8;

  const int lofs = lane * 8;                        // shorts

  f32x4 acc00 = {0.f, 0.f, 0.f, 0.f};
  f32x4 acc01 = acc00, acc10 = acc00, acc11 = acc00;

  for (int k0 = 0; k0 < Kext; k0 += 64) {
    const unsigned short* sA =
        (k0 < 512) ? (xh + k0) : (k0 < 1024) ? (xh + (k0 - 512)) : (xl + (k0 - 1024));
    load_lds16(sA + gA0, &As[c0 * 8]);
    load_lds16(sA + gA1, &As[c1 * 8]);
    load_lds16(Bt + k0 + gB0, &Bs[c0 * 8]);
    load_lds16(Bt + k0 + gB1, &Bs[c1 * 8]);
    __syncthreads();
    #pragma unroll
    for (int ks = 0; ks < 2; ks++) {
      short8v a0 = *(const short8v*)&As[(wr * 4 + ks) * 512 + lofs];
      short8v a1 = *(const short8v*)&As[(wr * 4 + 2 + ks) * 512 + lofs];
      short8v b0 = *(const short8v*)&Bs[(wc * 4 + ks) * 512 + lofs];
      short8v b1 = *(const short8v*)&Bs[(wc * 4 + 2 + ks) * 512 + lofs];
      acc00 = __builtin_amdgcn_mfma_f32_16x16x32_bf16(a0, b0, acc00, 0, 0, 0);
      acc01 = __builtin_amdgcn_mfma_f32_16x16x32_bf16(a0, b1, acc01, 0, 0, 0);
      acc10 = __builtin_amdgcn_mfma_f32_16x16x32_bf16(a1, b0, acc10, 0, 0, 0);
      acc11 = __builtin_amdgcn_mfma_f32_16x16x32_bf16(a1, b1, acc11, 0, 0, 0);
    }
    __syncthreads();
  }

  // epilogue: C/D layout col=lane&15, row=(lane>>4)*4+r  [m89-verified]
  const int colb = lane & 15;
  const int rowb = (lane >> 4) << 2;
  #pragma unroll
  for (int m = 0; m < 2; m++) {
    #pragma unroll
    for (int n = 0; n < 2; n++) {
      f32x4 a = (m == 0) ? (n == 0 ? acc00 : acc01) : (n == 0 ? acc10 : acc11);
      const int cl = wc * 32 + n * 16 + colb;
      #pragma unroll
      for (int r = 0; r < 4; r++) {
        const int gr = bm * 64 + wr * 32 + m * 16 + rowb + r;
        if (bn < 2) {
          const int gc = bn * 64 + cl;
          g1[(size_t)gr * DO + gc] = dinv1[gr] * a[r];
        } else {
          const int gc = (bn - 2) * 64 + cl;
          g2b[(size_t)gr * DO + gc] = f2bf(dinv2[gr] * a[r]);
        }
      }
    }
  }
}

// Fused spmm: 256 threads per node. LDS: redA 4KB + sidx 1KB -> 8 blocks/CU.
// Index row async-staged to LDS (global_load_lds) at entry; HBM latency
// hides under phase 1; phase-1 barrier (vmcnt drain) fences it.
// Phase 1 (cols 0:128): CSR gather over g1 (f32), 4-way edge split, float2/lane.
// Phase 2 (cols 128:256): LDS-index gather over g2b (bf16), 8-way k-split,
//                         uint2 (4 bf16) per lane, 32 lanes per row.
__global__ __launch_bounds__(256) void k_spmm(const float* __restrict__ g1,
                                              const unsigned* __restrict__ row_ptr,
                                              const unsigned* __restrict__ csr_src,
                                              const float* __restrict__ dinv1,
                                              const float* __restrict__ b1,
                                              const unsigned short* __restrict__ g2b,
                                              const unsigned short* __restrict__ adj2,
                                              const unsigned* __restrict__ deg2,
                                              const float* __restrict__ dinv2,
                                              const float* __restrict__ b2,
                                              float* __restrict__ out) {
  const int i = blockIdx.x, t = threadIdx.x;
  __shared__ float redA[8][128];
  __shared__ __align__(16) unsigned short sidx[A2S];   // 1 KB

  // issue full index-row stage now; completes under phase 1
  load_lds4(&adj2[(size_t)i * A2S + t * 2], &sidx[t * 2]);

  // ---- phase 1: 1-hop CSR ----
  {
    const int q = t >> 6, c = t & 63;
    const unsigned lo = row_ptr[i], hi = row_ptr[i + 1];
    float a0 = 0.f, a1 = 0.f;
    #pragma unroll 4
    for (unsigned e = lo + q; e < hi; e += 4) {
      unsigned j = csr_src[e];
      float2 v = *(const float2*)&g1[(size_t)j * DO + 2 * c];
      a0 += v.x; a1 += v.y;
    }
    redA[q][2 * c] = a0;
    redA[q][2 * c + 1] = a1;
    __syncthreads();                            // also drains the index stage
    if (t < 128) {
      float s = g1[(size_t)i * DO + t]          // self-loop term (dinv^2*h)
              + redA[0][t] + redA[1][t] + redA[2][t] + redA[3][t];
      out[(size_t)i * 256 + t] = 0.99f * (dinv1[i] * s + b1[t]);
    }
  }
  __syncthreads();

  // ---- phase 2: 2-hop via LDS-staged adj2 indices ----
  const unsigned total = deg2[i];
  const int q = t >> 5, c = t & 31;            // 8-way; uint2 = 4 bf16 per lane
  float a0 = 0.f, a1 = 0.f, a2 = 0.f, a3 = 0.f;
  #pragma unroll 4
  for (unsigned k = q; k < total; k += 8) {
    unsigned j = sidx[k];                       // LDS broadcast
    uint2 u = *(const uint2*)&g2b[(size_t)j * DO + 4 * c];
    a0 += __uint_as_float(u.x << 16);
    a1 += __uint_as_float(u.x & 0xffff0000u);
    a2 += __uint_as_float(u.y << 16);
    a3 += __uint_as_float(u.y & 0xffff0000u);
  }
  redA[q][4 * c]     = a0;
  redA[q][4 * c + 1] = a1;
  redA[q][4 * c + 2] = a2;
  redA[q][4 * c + 3] = a3;
  __syncthreads();
  if (t < 128) {
    float s = bf2f(g2b[(size_t)i * DO + t]);   // appended self-loop
    #pragma unroll
    for (int r = 0; r < 8; r++) s += redA[r][t];
    out[(size_t)i * 256 + 128 + t] = 0.01f * (dinv2[i] * s + b2[t]);
  }
}

// ---------------- launch ----------------

extern "C" void kernel_launch(void* const* d_in, const int* in_sizes, int n_in,
                              void* d_out, int out_size, void* d_ws, size_t ws_size,
                              hipStream_t stream) {
  const float* x  = (const float*)d_in[0];
  const int*   ei = (const int*)d_in[1];
  const float* W1 = (const float*)d_in[2];
  const float* b1 = (const float*)d_in[3];
  const float* W2 = (const float*)d_in[4];
  const float* b2 = (const float*)d_in[5];
  float* out = (float*)d_out;
  char* ws = (char*)d_ws;

  float* g1              = (float*)(ws + OFF_G1);
  unsigned short* g2b    = (unsigned short*)(ws + OFF_G2B);
  u64* AT                = (u64*)(ws + OFF_AT);
  unsigned short* adj2   = (unsigned short*)(ws + OFF_ADJ2);
  unsigned short* xh     = (unsigned short*)(ws + OFF_XH);
  unsigned short* xl     = (unsigned short*)(ws + OFF_XL);
  unsigned short* Bt     = (unsigned short*)(ws + OFF_BT);
  unsigned* cnt          = (unsigned*)(ws + OFF_CNT);
  unsigned* fill         = (unsigned*)(ws + OFF_FILL);
  unsigned* row_ptr      = (unsigned*)(ws + OFF_RP);
  unsigned* csr_src      = (unsigned*)(ws + OFF_CSR);
  float* dinv1           = (float*)(ws + OFF_DI1);
  float* dinv2           = (float*)(ws + OFF_DI2);
  unsigned* deg2         = (unsigned*)(ws + OFF_DEG2);

  k_zero<<<1024, 256, 0, stream>>>(AT, cnt, fill);
  k_hist<<<NE / 256, 256, 0, stream>>>(ei, cnt);
  k_scan<<<1, 1024, 0, stream>>>(cnt, row_ptr, dinv1);
  k_scatter<<<NE / 256, 256, 0, stream>>>(ei, row_ptr, fill, csr_src, AT);
  k_a2t<<<NN, 512, 0, stream>>>(AT, adj2, deg2, dinv2);
  k_prep<<<2080, 256, 0, stream>>>(x, W1, W2, xh, xl, Bt);
  dim3 gg(NN / 64, 4);
  k_gemm<<<gg, 256, 0, stream>>>(xh, xl, Bt, dinv1, dinv2, g1, g2b);
  k_spmm<<<NN, 256, 0, stream>>>(g1, row_ptr, csr_src, dinv1, b1,
                                 g2b, adj2, deg2, dinv2, b2, out);
}